// Round 1
// baseline (418.038 us; speedup 1.0000x reference)
//
#include <hip/hip_runtime.h>

#define B_ 16
#define C_ 256
#define N_ 4096
#define NTB 16                  // n per subtile
#define NSUB 4                  // subtiles per block
#define NBLK (N_ / (NTB * NSUB))  // 64 n-blocks per batch

// ---------------- W transpose: Wt[i][c] = W[c][i] ----------------
__global__ void wt_transpose(const float* __restrict__ W, float* __restrict__ Wt) {
    int i = blockIdx.x;   // 0..255
    int c = threadIdx.x;  // 0..255
    Wt[i * C_ + c] = W[c * C_ + i];
}

// ---------------- phase1: d = W@x, dotprod, per-block argmax ----------------
// grid: B_*NBLK blocks, 256 threads.
// thread tc = tid&63 handles channels c = tc + 64*j (j=0..3)
// thread tn = tid>>6 handles n-lanes tn*4 .. tn*4+3 within the 16-n subtile
__global__ __launch_bounds__(256) void phase1(
    const float* __restrict__ x, const float* __restrict__ Wt,
    float* __restrict__ bval, int* __restrict__ bidx)
{
    __shared__ float Xs[C_ * 3 * NTB];   // 48 KB: [i][k][n16]
    __shared__ float rv[4][C_];          // 4 KB  [tn][c]
    __shared__ int   ri[4][C_];          // 4 KB

    const int tid = threadIdx.x;
    const int tc  = tid & 63;
    const int tn  = tid >> 6;            // 0..3
    const int b   = blockIdx.x >> 6;
    const int nb  = blockIdx.x & (NBLK - 1);
    const int n_base = nb * (NTB * NSUB);

    const float* xb = x + (size_t)b * C_ * 3 * N_;

    // running best per reducer thread (threads 0..63 use these at the end)
    float best_v[4];
    int   best_i[4];
#pragma unroll
    for (int j = 0; j < 4; ++j) { best_v[j] = -__builtin_inff(); best_i[j] = 0; }

    for (int s = 0; s < NSUB; ++s) {
        const int n0 = n_base + s * NTB;
        __syncthreads();  // previous subtile's Xs readers are done
        // stage X tile: 768 rows x 16 floats = 3072 float4, 12 per thread
#pragma unroll
        for (int t = 0; t < 12; ++t) {
            int fid = t * 256 + tid;
            int r = fid >> 2;      // row (i*3+k) 0..767
            int q = fid & 3;       // which float4 in the 16-n row
            float4 v = *(const float4*)(xb + (size_t)r * N_ + n0 + q * 4);
            *(float4*)&Xs[r * NTB + q * 4] = v;
        }
        __syncthreads();

        float acc[4][3][4];  // [j][k][nn]  = d[c, k, n]
#pragma unroll
        for (int j = 0; j < 4; ++j)
#pragma unroll
            for (int k = 0; k < 3; ++k)
#pragma unroll
                for (int nn = 0; nn < 4; ++nn) acc[j][k][nn] = 0.f;

#pragma unroll 2
        for (int i = 0; i < C_; ++i) {
            float w[4];
#pragma unroll
            for (int j = 0; j < 4; ++j) w[j] = Wt[i * C_ + tc + 64 * j];
#pragma unroll
            for (int k = 0; k < 3; ++k) {
                float4 xv = *(const float4*)&Xs[(i * 3 + k) * NTB + tn * 4];
                float xa[4] = {xv.x, xv.y, xv.z, xv.w};
#pragma unroll
                for (int j = 0; j < 4; ++j)
#pragma unroll
                    for (int nn = 0; nn < 4; ++nn)
                        acc[j][k][nn] += w[j] * xa[nn];
            }
        }

        // dotprod over k, then local argmax over this thread's 4 n
#pragma unroll
        for (int j = 0; j < 4; ++j) {
            const int c = tc + 64 * j;
            float dp[4] = {0.f, 0.f, 0.f, 0.f};
#pragma unroll
            for (int k = 0; k < 3; ++k) {
                float4 xv = *(const float4*)&Xs[(c * 3 + k) * NTB + tn * 4];
                float xa[4] = {xv.x, xv.y, xv.z, xv.w};
#pragma unroll
                for (int nn = 0; nn < 4; ++nn) dp[nn] += xa[nn] * acc[j][k][nn];
            }
            float lv = dp[0]; int li = n0 + tn * 4;
#pragma unroll
            for (int nn = 1; nn < 4; ++nn) {
                if (dp[nn] > lv) { lv = dp[nn]; li = n0 + tn * 4 + nn; }  // strict > keeps first
            }
            rv[tn][c] = lv;
            ri[tn][c] = li;
        }
        __syncthreads();

        // threads 0..63 fold the 4 tn groups into the running best (index-aware)
        if (tid < 64) {
#pragma unroll
            for (int j = 0; j < 4; ++j) {
                const int c = tid + 64 * j;
#pragma unroll
                for (int t = 0; t < 4; ++t) {
                    float v = rv[t][c]; int ii = ri[t][c];
                    if (v > best_v[j] || (v == best_v[j] && ii < best_i[j])) {
                        best_v[j] = v; best_i[j] = ii;
                    }
                }
            }
        }
    }

    if (tid < 64) {
#pragma unroll
        for (int j = 0; j < 4; ++j) {
            const int c = tid + 64 * j;
            bval[((size_t)b * C_ + c) * NBLK + nb] = best_v[j];
            bidx[((size_t)b * C_ + c) * NBLK + nb] = best_i[j];
        }
    }
}

// ---------------- phase2: final argmax reduce + gather ----------------
// grid: B_*C_ blocks of 64 threads (one wave per (b,c))
__global__ void phase2(const float* __restrict__ x,
                       const float* __restrict__ bval, const int* __restrict__ bidx,
                       float* __restrict__ out)
{
    const int bc = blockIdx.x;          // b*256 + c
    const int lane = threadIdx.x;       // 0..63
    const float* v = bval + (size_t)bc * NBLK;
    const int*  ii = bidx + (size_t)bc * NBLK;

    float bv = -__builtin_inff(); int bi = 0x7fffffff;
    for (int t = lane; t < NBLK; t += 64) {
        float vv = v[t]; int id = ii[t];
        if (vv > bv || (vv == bv && id < bi)) { bv = vv; bi = id; }
    }
#pragma unroll
    for (int off = 32; off; off >>= 1) {
        float ov = __shfl_down(bv, off);
        int   oi = __shfl_down(bi, off);
        if (ov > bv || (ov == bv && oi < bi)) { bv = ov; bi = oi; }
    }
    if (lane == 0) {
        const int b = bc >> 8, c = bc & 255;
#pragma unroll
        for (int k = 0; k < 3; ++k)
            out[bc * 3 + k] = x[(((size_t)b * C_ + c) * 3 + k) * N_ + bi];
    }
}

extern "C" void kernel_launch(void* const* d_in, const int* in_sizes, int n_in,
                              void* d_out, int out_size, void* d_ws, size_t ws_size,
                              hipStream_t stream) {
    const float* x = (const float*)d_in[0];
    const float* W = (const float*)d_in[1];
    float* out = (float*)d_out;

    float* Wt   = (float*)d_ws;                                   // 256 KB
    float* bval = (float*)((char*)d_ws + (size_t)C_ * C_ * 4);    // 1 MB
    int*   bidx = (int*)((char*)d_ws + (size_t)C_ * C_ * 4
                         + (size_t)B_ * C_ * NBLK * 4);           // 1 MB

    wt_transpose<<<C_, C_, 0, stream>>>(W, Wt);
    phase1<<<B_ * NBLK, 256, 0, stream>>>(x, Wt, bval, bidx);
    phase2<<<B_ * C_, 64, 0, stream>>>(x, bval, bidx, out);
}

// Round 2
// 169.971 us; speedup vs baseline: 2.4595x; 2.4595x over previous
//
#include <hip/hip_runtime.h>

typedef _Float16 half8  __attribute__((ext_vector_type(8)));
typedef _Float16 half2v __attribute__((ext_vector_type(2)));
typedef float    f32x4  __attribute__((ext_vector_type(4)));

#define B_ 16
#define C_ 256
#define N_ 4096
#define TAU 1e-2f

// ---------- top-2 merge (desc order, first-index wins on equal value) ----------
__device__ __forceinline__ void top2_merge(float& v1, int& i1, float& v2, int& i2,
                                           float w1, int j1, float w2, int j2) {
    bool bwin = (w1 > v1) || (w1 == v1 && j1 < i1);
    float t1 = bwin ? w1 : v1; int ti1 = bwin ? j1 : i1;
    float lv = bwin ? v1 : w1; int li  = bwin ? i1 : j1;   // loser's top1
    float wv = bwin ? w2 : v2; int wi  = bwin ? i2 : j2;   // winner's top2
    bool c2 = (lv > wv) || (lv == wv && li < wi);
    v2 = c2 ? lv : wv; i2 = c2 ? li : wi;
    v1 = t1; i1 = ti1;
}

// ---------- prep: W' = 16*W -> f16 hi/lo, stored A-fragment-major ----------
// f16 index: ((cb*8+s)*64 + l)*8 + j ;  c = cb*16+(l&15), i = s*32+(l>>4)*8+j
__global__ void prep_w(const float* __restrict__ W,
                       _Float16* __restrict__ WfH, _Float16* __restrict__ WfL) {
    int t = blockIdx.x * 256 + threadIdx.x;  // 0..8191
    int l = t & 63, g = t >> 6;
    int s = g & 7, cb = g >> 3;              // cb 0..15
    int c = cb * 16 + (l & 15);
    int i0 = s * 32 + (l >> 4) * 8;
    int base = ((cb * 8 + s) * 64 + l) * 8;
#pragma unroll
    for (int j = 0; j < 8; ++j) {
        float w = 16.0f * W[c * C_ + i0 + j];   // x16 keeps W_lo out of f16-denormal range
        _Float16 h  = (_Float16)w;
        _Float16 lo = (_Float16)(w - (float)h);
        WfH[base + j] = h;
        WfL[base + j] = lo;
    }
}

// ---------- main: d = W'@x via 3-pass f16-split MFMA, dp, per-32n top-2 ----------
// grid: 16 b * 128 n-chunks (32 n each); 256 threads = 4 waves, wave owns 64c x 32n
__global__ __launch_bounds__(256) void vn_main(
    const float* __restrict__ x,
    const _Float16* __restrict__ WfH, const _Float16* __restrict__ WfL,
    float4* __restrict__ btop)
{
    __shared__ __align__(16) _Float16 XH[3072];   // [k][nf][L=64][j=8] frag-linear
    __shared__ __align__(16) _Float16 XL[3072];

    const int tid  = threadIdx.x;
    const int lane = tid & 63;
    const int wid  = tid >> 6;
    const int b    = blockIdx.x >> 7;
    const int nb   = blockIdx.x & 127;
    const int n0   = nb << 5;

    const float* xb = x + ((b * 768) << 12);      // b*256*3*4096

    f32x4 acc[3][4][2];
    const f32x4 zero = {0.f, 0.f, 0.f, 0.f};
#pragma unroll
    for (int k = 0; k < 3; ++k)
#pragma unroll
        for (int cf = 0; cf < 4; ++cf)
#pragma unroll
            for (int nf = 0; nf < 2; ++nf) acc[k][cf][nf] = zero;

    const int il0 = (tid >> 4) << 1;   // staging: i-pair 0,2,..,30
    const int nn0 = (tid & 15) << 1;   // staging: n-pair 0,2,..,30

    for (int s = 0; s < 8; ++s) {
        // A-fragments straight from global (L2-resident, frag-major -> perfectly coalesced)
        half8 ah[4], al[4];
#pragma unroll
        for (int cf = 0; cf < 4; ++cf) {
            int cb  = (wid << 2) + cf;
            int off = (((cb << 3) + s) * 64 + lane) * 8;
            ah[cf] = *(const half8*)(WfH + off);
            al[cf] = *(const half8*)(WfL + off);
        }
        // stage loads: 2 rows (il0, il0+1) x 2 n (nn0, nn0+1) x 3 k
        float2 v[3][2];
#pragma unroll
        for (int k = 0; k < 3; ++k)
#pragma unroll
            for (int rr = 0; rr < 2; ++rr)
                v[k][rr] = *(const float2*)(xb + (((32 * s + il0 + rr) * 3 + k) << 12) + n0 + nn0);

        __syncthreads();   // previous iteration's LDS readers done
#pragma unroll
        for (int k = 0; k < 3; ++k)
#pragma unroll
            for (int m = 0; m < 2; ++m) {
                float a0 = m ? v[k][0].y : v[k][0].x;   // row il0
                float a1 = m ? v[k][1].y : v[k][1].x;   // row il0+1
                _Float16 h0 = (_Float16)a0, h1 = (_Float16)a1;
                _Float16 l0 = (_Float16)(a0 - (float)h0);
                _Float16 l1 = (_Float16)(a1 - (float)h1);
                int n  = nn0 + m;
                int nf = n >> 4;
                int l2 = ((il0 >> 3) << 4) + (n & 15);
                int idx = ((k * 2 + nf) * 64 + l2) * 4 + ((il0 & 7) >> 1);  // half2 units
                ((half2v*)XH)[idx] = (half2v){h0, h1};
                ((half2v*)XL)[idx] = (half2v){l0, l1};
            }
        __syncthreads();

        // MFMA: hi*hi + lo*hi + hi*lo (same accumulator; all in W'=16W scale)
#pragma unroll
        for (int k = 0; k < 3; ++k)
#pragma unroll
            for (int nf = 0; nf < 2; ++nf) {
                const half8 bh = *(const half8*)(XH + ((k * 2 + nf) * 64 + lane) * 8);
                const half8 bl = *(const half8*)(XL + ((k * 2 + nf) * 64 + lane) * 8);
#pragma unroll
                for (int cf = 0; cf < 4; ++cf) {
                    acc[k][cf][nf] = __builtin_amdgcn_mfma_f32_16x16x32_f16(ah[cf], bh, acc[k][cf][nf], 0, 0, 0);
                    acc[k][cf][nf] = __builtin_amdgcn_mfma_f32_16x16x32_f16(al[cf], bh, acc[k][cf][nf], 0, 0, 0);
                    acc[k][cf][nf] = __builtin_amdgcn_mfma_f32_16x16x32_f16(ah[cf], bl, acc[k][cf][nf], 0, 0, 0);
                }
            }
    }

    // epilogue: dp = sum_k x*d / 16, per-c-row top-2 over this 32-n window
    const int g   = lane >> 4;
    const int t16 = lane & 15;
    const int c0  = wid << 6;
#pragma unroll
    for (int cf = 0; cf < 4; ++cf) {
#pragma unroll
        for (int r = 0; r < 4; ++r) {
            int c = c0 + cf * 16 + g * 4 + r;
            float dpA = 0.f, dpB = 0.f;
#pragma unroll
            for (int k = 0; k < 3; ++k) {
                const float* row = x + (((b * C_ + c) * 3 + k) << 12) + n0;
                dpA += row[t16]      * acc[k][cf][0][r];
                dpB += row[16 + t16] * acc[k][cf][1][r];
            }
            dpA *= 0.0625f; dpB *= 0.0625f;
            int iA = n0 + t16, iB = n0 + 16 + t16;
            float v1, v2; int i1, i2;
            if (dpB > dpA) { v1 = dpB; i1 = iB; v2 = dpA; i2 = iA; }
            else           { v1 = dpA; i1 = iA; v2 = dpB; i2 = iB; }
#pragma unroll
            for (int m = 1; m <= 8; m <<= 1) {
                float w1 = __shfl_xor(v1, m), w2 = __shfl_xor(v2, m);
                int   j1 = __shfl_xor(i1, m), j2 = __shfl_xor(i2, m);
                top2_merge(v1, i1, v2, i2, w1, j1, w2, j2);
            }
            if (t16 == 0)
                btop[(b * C_ + c) * 128 + nb] =
                    make_float4(v1, __int_as_float(i1), v2, __int_as_float(i2));
        }
    }
}

// ---------- phase2: global top-2 merge, certify or exact-recompute, gather ----------
// grid: 4096 blocks x 64 threads (one wave per (b,c))
__global__ void phase2(const float* __restrict__ x, const float* __restrict__ W,
                       const float4* __restrict__ btop, float* __restrict__ out)
{
    const int bc = blockIdx.x;          // b*256 + c
    const int b = bc >> 8, c = bc & 255;
    const int lane = threadIdx.x;

    float4 e0 = btop[bc * 128 + lane];
    float4 e1 = btop[bc * 128 + 64 + lane];

    float v1 = e0.x; int i1 = __float_as_int(e0.y);
    float v2 = e0.z; int i2 = __float_as_int(e0.w);
    top2_merge(v1, i1, v2, i2, e1.x, __float_as_int(e1.y), e1.z, __float_as_int(e1.w));
#pragma unroll
    for (int m = 1; m <= 32; m <<= 1) {
        float w1 = __shfl_xor(v1, m), w2 = __shfl_xor(v2, m);
        int   j1 = __shfl_xor(i1, m), j2 = __shfl_xor(i2, m);
        top2_merge(v1, i1, v2, i2, w1, j1, w2, j2);
    }

    int winner = i1;
    if (!(v1 - v2 > TAU)) {
        // rare: exact fp32 recompute of every 32-n window whose max is within TAU of v1
        float bv = -3.4e38f; int bi = 0x7fffffff;
#pragma unroll
        for (int t = 0; t < 2; ++t) {
            float4 e = t ? e1 : e0;
            bool flag = (e.x >= v1 - TAU);
            unsigned long long mask = __ballot(flag);
            while (mask) {
                int src = __builtin_ctzll(mask);
                mask &= mask - 1;
                int region = src + t * 64;
                int nb0 = region * 32;
                for (int ch = 0; ch < 4; ++ch) {
                    int nbase = nb0 + ch * 8;
                    float accv[8];
#pragma unroll
                    for (int m2 = 0; m2 < 8; ++m2) accv[m2] = 0.f;
                    float xc[3][8];
#pragma unroll
                    for (int k = 0; k < 3; ++k) {
                        const float* p = x + ((bc * 3 + k) << 12) + nbase;
#pragma unroll
                        for (int m2 = 0; m2 < 8; ++m2) xc[k][m2] = p[m2];
                    }
                    for (int q = 0; q < 4; ++q) {
                        int i = lane + (q << 6);
                        float wq = W[c * C_ + i];
#pragma unroll
                        for (int k = 0; k < 3; ++k) {
                            const float* p = x + (((b * C_ + i) * 3 + k) << 12) + nbase;
#pragma unroll
                            for (int m2 = 0; m2 < 8; ++m2)
                                accv[m2] += wq * p[m2] * xc[k][m2];
                        }
                    }
#pragma unroll
                    for (int m2 = 0; m2 < 8; ++m2) {
#pragma unroll
                        for (int mm = 1; mm <= 32; mm <<= 1)
                            accv[m2] += __shfl_xor(accv[m2], mm);
                        int n = nbase + m2;
                        if (accv[m2] > bv || (accv[m2] == bv && n < bi)) { bv = accv[m2]; bi = n; }
                    }
                }
            }
        }
        winner = bi;
    }

    if (lane < 3)
        out[bc * 3 + lane] = x[((bc * 3 + lane) << 12) + winner];
}

extern "C" void kernel_launch(void* const* d_in, const int* in_sizes, int n_in,
                              void* d_out, int out_size, void* d_ws, size_t ws_size,
                              hipStream_t stream) {
    const float* x = (const float*)d_in[0];
    const float* W = (const float*)d_in[1];
    float* out = (float*)d_out;

    _Float16* WfH = (_Float16*)d_ws;                        // 128 KB
    _Float16* WfL = (_Float16*)((char*)d_ws + 131072);      // 128 KB
    float4*   btop = (float4*)((char*)d_ws + 262144);       // 8 MB: [b*C_+c][128] (v1,i1,v2,i2)

    prep_w<<<32, 256, 0, stream>>>(W, WfH, WfL);
    vn_main<<<B_ * 128, 256, 0, stream>>>(x, WfH, WfL, btop);
    phase2<<<B_ * C_, 64, 0, stream>>>(x, W, btop, out);
}

// Round 3
// 160.701 us; speedup vs baseline: 2.6013x; 1.0577x over previous
//
#include <hip/hip_runtime.h>

typedef _Float16 half8  __attribute__((ext_vector_type(8)));
typedef _Float16 half2v __attribute__((ext_vector_type(2)));
typedef float    f32x4  __attribute__((ext_vector_type(4)));

#define B_ 16
#define C_ 256
#define N_ 4096
#define TAU 1e-2f

// ---------- top-2 merge (desc order, first-index wins on equal value) ----------
__device__ __forceinline__ void top2_merge(float& v1, int& i1, float& v2, int& i2,
                                           float w1, int j1, float w2, int j2) {
    bool bwin = (w1 > v1) || (w1 == v1 && j1 < i1);
    float t1 = bwin ? w1 : v1; int ti1 = bwin ? j1 : i1;
    float lv = bwin ? v1 : w1; int li  = bwin ? i1 : j1;   // loser's top1
    float wv = bwin ? w2 : v2; int wi  = bwin ? i2 : j2;   // winner's top2
    bool c2 = (lv > wv) || (lv == wv && li < wi);
    v2 = c2 ? lv : wv; i2 = c2 ? li : wi;
    v1 = t1; i1 = ti1;
}

// ---------- prep: W' = 16*W -> f16 hi/lo, stored A-fragment-major ----------
// f16 index: ((cb*8+s)*64 + l)*8 + j ;  c = cb*16+(l&15), i = s*32+(l>>4)*8+j
__global__ void prep_w(const float* __restrict__ W,
                       _Float16* __restrict__ WfH, _Float16* __restrict__ WfL) {
    int t = blockIdx.x * 256 + threadIdx.x;  // 0..8191
    int l = t & 63, g = t >> 6;
    int s = g & 7, cb = g >> 3;              // cb 0..15
    int c = cb * 16 + (l & 15);
    int i0 = s * 32 + (l >> 4) * 8;
    int base = ((cb * 8 + s) * 64 + l) * 8;
#pragma unroll
    for (int j = 0; j < 8; ++j) {
        float w = 16.0f * W[c * C_ + i0 + j];   // x16 keeps W_lo out of f16-denormal range
        _Float16 h  = (_Float16)w;
        _Float16 lo = (_Float16)(w - (float)h);
        WfH[base + j] = h;
        WfL[base + j] = lo;
    }
}

// ---------- main: d = W'@x via 3-pass f16-split MFMA, dp, per-32n top-2 ----------
// grid: 16 b * 128 n-chunks (32 n each); 256 threads = 4 waves, wave owns 64c x 32n
// Software-pipelined: LDS double-buffer, reg-dbuf W frags, 1 barrier per K-slice.
__global__ __launch_bounds__(256, 2) void vn_main(
    const float* __restrict__ x,
    const _Float16* __restrict__ WfH, const _Float16* __restrict__ WfL,
    float4* __restrict__ btop)
{
    __shared__ __align__(16) _Float16 XH[2][3072];   // [buf][ (k*2+nf)*64 + lane ]*8+j
    __shared__ __align__(16) _Float16 XL[2][3072];

    const int tid  = threadIdx.x;
    const int lane = tid & 63;
    const int wid  = tid >> 6;
    const int b    = blockIdx.x >> 7;
    const int nb   = blockIdx.x & 127;
    const int n0   = nb << 5;

    const float* xb = x + ((size_t)(b * 768) << 12);      // b*256*3*4096

    f32x4 acc[3][4][2];
    const f32x4 zero = {0.f, 0.f, 0.f, 0.f};
#pragma unroll
    for (int k = 0; k < 3; ++k)
#pragma unroll
        for (int cf = 0; cf < 4; ++cf)
#pragma unroll
            for (int nf = 0; nf < 2; ++nf) acc[k][cf][nf] = zero;

    const int il0 = (tid >> 4) << 1;   // staging: i-pair 0,2,..,30
    const int nn0 = (tid & 15) << 1;   // staging: n-pair 0,2,..,30

    float2 v[3][2];
    half8 ah[2][4], al[2][4];

#define LOADX(S)                                                                   \
    do {                                                                           \
        _Pragma("unroll") for (int k = 0; k < 3; ++k)                              \
        _Pragma("unroll") for (int rr = 0; rr < 2; ++rr)                           \
            v[k][rr] = *(const float2*)(xb +                                       \
                (((32 * (S) + il0 + rr) * 3 + k) << 12) + n0 + nn0);               \
    } while (0)

#define WRITEX(BUF)                                                                \
    do {                                                                           \
        _Pragma("unroll") for (int k = 0; k < 3; ++k)                              \
        _Pragma("unroll") for (int m = 0; m < 2; ++m) {                            \
            float a0 = m ? v[k][0].y : v[k][0].x;                                  \
            float a1 = m ? v[k][1].y : v[k][1].x;                                  \
            _Float16 h0 = (_Float16)a0, h1 = (_Float16)a1;                         \
            _Float16 l0 = (_Float16)(a0 - (float)h0);                              \
            _Float16 l1 = (_Float16)(a1 - (float)h1);                              \
            int n  = nn0 + m;                                                      \
            int nf = n >> 4;                                                       \
            int l2 = ((il0 >> 3) << 4) + (n & 15);                                 \
            int idx = ((k * 2 + nf) * 64 + l2) * 4 + ((il0 & 7) >> 1);             \
            ((half2v*)XH[(BUF)])[idx] = (half2v){h0, h1};                          \
            ((half2v*)XL[(BUF)])[idx] = (half2v){l0, l1};                          \
        }                                                                          \
    } while (0)

#define LOADW(S, P)                                                                \
    do {                                                                           \
        _Pragma("unroll") for (int cf = 0; cf < 4; ++cf) {                         \
            int cb  = (wid << 2) + cf;                                             \
            int off = (((cb << 3) + (S)) * 64 + lane) * 8;                         \
            ah[(P)][cf] = *(const half8*)(WfH + off);                              \
            al[(P)][cf] = *(const half8*)(WfL + off);                              \
        }                                                                          \
    } while (0)

    // prologue: slice 0 into buf 0, W frags for slice 0 into parity 0
    LOADW(0, 0);
    LOADX(0);
    WRITEX(0);

#pragma unroll
    for (int s = 0; s < 8; ++s) {
        const int cur = s & 1;
        if (s < 7) {
            LOADX(s + 1);            // global loads issue now, land during MFMA
            LOADW(s + 1, cur ^ 1);   // W frags for next slice (L2-resident)
        }
        __syncthreads();             // buf[cur] fully written
        // MFMA: hi*hi + lo*hi + hi*lo (all in W'=16W scale)
#pragma unroll
        for (int k = 0; k < 3; ++k)
#pragma unroll
            for (int nf = 0; nf < 2; ++nf) {
                const half8 bh = *(const half8*)(&XH[cur][((k * 2 + nf) * 64 + lane) * 8]);
                const half8 bl = *(const half8*)(&XL[cur][((k * 2 + nf) * 64 + lane) * 8]);
#pragma unroll
                for (int cf = 0; cf < 4; ++cf) {
                    acc[k][cf][nf] = __builtin_amdgcn_mfma_f32_16x16x32_f16(ah[cur][cf], bh, acc[k][cf][nf], 0, 0, 0);
                    acc[k][cf][nf] = __builtin_amdgcn_mfma_f32_16x16x32_f16(al[cur][cf], bh, acc[k][cf][nf], 0, 0, 0);
                    acc[k][cf][nf] = __builtin_amdgcn_mfma_f32_16x16x32_f16(ah[cur][cf], bl, acc[k][cf][nf], 0, 0, 0);
                }
            }
        if (s < 7) WRITEX(cur ^ 1);  // convert+write next slice after MFMA issue
    }

    // epilogue: dp = sum_k x*d / 16, per-c-row top-2 over this 32-n window
    const int g   = lane >> 4;
    const int t16 = lane & 15;
    const int c0  = wid << 6;
#pragma unroll
    for (int cf = 0; cf < 4; ++cf) {
#pragma unroll
        for (int r = 0; r < 4; ++r) {
            int c = c0 + cf * 16 + g * 4 + r;
            float dpA = 0.f, dpB = 0.f;
#pragma unroll
            for (int k = 0; k < 3; ++k) {
                const float* row = x + (((b * C_ + c) * 3 + k) << 12) + n0;
                dpA += row[t16]      * acc[k][cf][0][r];
                dpB += row[16 + t16] * acc[k][cf][1][r];
            }
            dpA *= 0.0625f; dpB *= 0.0625f;
            int iA = n0 + t16, iB = n0 + 16 + t16;
            float v1, v2; int i1, i2;
            if (dpB > dpA) { v1 = dpB; i1 = iB; v2 = dpA; i2 = iA; }
            else           { v1 = dpA; i1 = iA; v2 = dpB; i2 = iB; }
#pragma unroll
            for (int m = 1; m <= 8; m <<= 1) {
                float w1 = __shfl_xor(v1, m), w2 = __shfl_xor(v2, m);
                int   j1 = __shfl_xor(i1, m), j2 = __shfl_xor(i2, m);
                top2_merge(v1, i1, v2, i2, w1, j1, w2, j2);
            }
            if (t16 == 0)
                btop[(b * C_ + c) * 128 + nb] =
                    make_float4(v1, __int_as_float(i1), v2, __int_as_float(i2));
        }
    }
}

// ---------- phase2: global top-2 merge, certify or exact-recompute, gather ----------
// grid: 4096 blocks x 64 threads (one wave per (b,c))
__global__ void phase2(const float* __restrict__ x, const float* __restrict__ W,
                       const float4* __restrict__ btop, float* __restrict__ out)
{
    const int bc = blockIdx.x;          // b*256 + c
    const int b = bc >> 8, c = bc & 255;
    const int lane = threadIdx.x;

    float4 e0 = btop[bc * 128 + lane];
    float4 e1 = btop[bc * 128 + 64 + lane];

    float v1 = e0.x; int i1 = __float_as_int(e0.y);
    float v2 = e0.z; int i2 = __float_as_int(e0.w);
    top2_merge(v1, i1, v2, i2, e1.x, __float_as_int(e1.y), e1.z, __float_as_int(e1.w));
#pragma unroll
    for (int m = 1; m <= 32; m <<= 1) {
        float w1 = __shfl_xor(v1, m), w2 = __shfl_xor(v2, m);
        int   j1 = __shfl_xor(i1, m), j2 = __shfl_xor(i2, m);
        top2_merge(v1, i1, v2, i2, w1, j1, w2, j2);
    }

    int winner = i1;
    if (!(v1 - v2 > TAU)) {
        // rare: exact fp32 recompute of every 32-n window whose max is within TAU of v1
        float bv = -3.4e38f; int bi = 0x7fffffff;
#pragma unroll
        for (int t = 0; t < 2; ++t) {
            float4 e = t ? e1 : e0;
            bool flag = (e.x >= v1 - TAU);
            unsigned long long mask = __ballot(flag);
            while (mask) {
                int src = __builtin_ctzll(mask);
                mask &= mask - 1;
                int region = src + t * 64;
                int nb0 = region * 32;
                for (int ch = 0; ch < 4; ++ch) {
                    int nbase = nb0 + ch * 8;
                    float accv[8];
#pragma unroll
                    for (int m2 = 0; m2 < 8; ++m2) accv[m2] = 0.f;
                    float xc[3][8];
#pragma unroll
                    for (int k = 0; k < 3; ++k) {
                        const float* p = x + ((bc * 3 + k) << 12) + nbase;
#pragma unroll
                        for (int m2 = 0; m2 < 8; ++m2) xc[k][m2] = p[m2];
                    }
                    for (int q = 0; q < 4; ++q) {
                        int i = lane + (q << 6);
                        float wq = W[c * C_ + i];
#pragma unroll
                        for (int k = 0; k < 3; ++k) {
                            const float* p = x + (((b * C_ + i) * 3 + k) << 12) + nbase;
#pragma unroll
                            for (int m2 = 0; m2 < 8; ++m2)
                                accv[m2] += wq * p[m2] * xc[k][m2];
                        }
                    }
#pragma unroll
                    for (int m2 = 0; m2 < 8; ++m2) {
#pragma unroll
                        for (int mm = 1; mm <= 32; mm <<= 1)
                            accv[m2] += __shfl_xor(accv[m2], mm);
                        int n = nbase + m2;
                        if (accv[m2] > bv || (accv[m2] == bv && n < bi)) { bv = accv[m2]; bi = n; }
                    }
                }
            }
        }
        winner = bi;
    }

    if (lane < 3)
        out[bc * 3 + lane] = x[((bc * 3 + lane) << 12) + winner];
}

extern "C" void kernel_launch(void* const* d_in, const int* in_sizes, int n_in,
                              void* d_out, int out_size, void* d_ws, size_t ws_size,
                              hipStream_t stream) {
    const float* x = (const float*)d_in[0];
    const float* W = (const float*)d_in[1];
    float* out = (float*)d_out;

    _Float16* WfH = (_Float16*)d_ws;                        // 128 KB
    _Float16* WfL = (_Float16*)((char*)d_ws + 131072);      // 128 KB
    float4*   btop = (float4*)((char*)d_ws + 262144);       // 8 MB: [b*C_+c][128] (v1,i1,v2,i2)

    prep_w<<<32, 256, 0, stream>>>(W, WfH, WfL);
    vn_main<<<B_ * 128, 256, 0, stream>>>(x, WfH, WfL, btop);
    phase2<<<B_ * C_, 64, 0, stream>>>(x, W, btop, out);
}